// Round 17
// baseline (1085.709 us; speedup 1.0000x reference)
//
#include <hip/hip_runtime.h>
#include <hip/hip_bf16.h>
#include <cstdint>
#include <cstddef>

constexpr int V_NODES = 100000;
constexpr float NEG = 0.2f;
constexpr float LN_EPS = 1e-5f;
typedef __hip_bfloat16 bf16;

typedef __attribute__((ext_vector_type(8))) short short8v;
typedef __attribute__((ext_vector_type(4))) float f32x4;

__device__ inline float bflo(unsigned u){ return __uint_as_float(u << 16); }
__device__ inline float bfhi(unsigned u){ return __uint_as_float(u & 0xffff0000u); }
__device__ inline unsigned short f2bu(float x){ bf16 h = __float2bfloat16(x); return *reinterpret_cast<unsigned short*>(&h); }
__device__ inline unsigned bfpk(float x, float y){ return (unsigned)f2bu(x) | ((unsigned)f2bu(y) << 16); }

__device__ inline f32x4 mfma16(short8v a, short8v b, f32x4 c){
  return __builtin_amdgcn_mfma_f32_16x16x32_bf16(a, b, c, 0, 0, 0);
}

// fast gates: limit-correct at +/-inf (exp->inf => rcp->0)
__device__ inline float sigm_f(float v){ return __builtin_amdgcn_rcpf(1.f + __expf(-v)); }
__device__ inline float tanh_f(float t){ return 1.f - 2.f*__builtin_amdgcn_rcpf(__expf(2.f*t) + 1.f); }

// ---- weight prep for MFMA gemms: frag-major layout (VERIFIED R2) ----
__global__ __launch_bounds__(256) void wprep_gf(const float* __restrict__ W,
                                                bf16* __restrict__ Wf, int K){
  int tid = blockIdx.x*256 + threadIdx.x;   // over K*256
  if (tid >= K*256) return;
  int fi = tid >> 9, rem = tid & 511;
  int lane = rem >> 3, i = rem & 7;
  int ks = fi >> 4, nt = fi & 15;
  int n = nt*16 + (lane & 15);
  int k = ks*32 + ((lane >> 4) << 3) + i;
  Wf[tid] = __float2bfloat16(W[(size_t)k*256 + n]);
}

// ---- GAT weight prep with head-grouping permutation sigma (VERIFIED R7) ----
__global__ __launch_bounds__(256) void wprep_gp(const float* __restrict__ W,
                                                bf16* __restrict__ Wf, int K){
  int tid = blockIdx.x*256 + threadIdx.x;   // over K*256
  if (tid >= K*256) return;
  int fi = tid >> 9, rem = tid & 511;
  int lane = rem >> 3, i = rem & 7;
  int ks = fi >> 4, nt = fi & 15;
  int n = nt*16 + (lane & 15);
  int ns = (((n & 63) >> 4) << 6) + ((n & 15) << 2) + (n >> 6);   // sigma(n)
  int k = ks*32 + ((lane >> 4) << 3) + i;
  Wf[tid] = __float2bfloat16(W[(size_t)k*256 + ns]);
}

// ---- GRU B-matrix compose in PLAIN u-space (VERIFIED R4): Bm[320][256] f32 ----
__global__ __launch_bounds__(256) void wprep_bu(const float* __restrict__ Wih,
                                                const float* __restrict__ Whh,
                                                float* __restrict__ Bm){
  int tid = blockIdx.x*256 + threadIdx.x;   // over 320*256 = 81920
  if (tid >= 81920) return;
  int k = tid >> 8, n = tid & 255;
  float v = 0.f;
  if (k < 256) {
    if (n < 192) v = Wih[(size_t)n*256 + k];
  } else {
    int kh = k - 256;
    if (n < 128)       v = Whh[(size_t)n*64 + kh];
    else if (n >= 192) v = Whh[(size_t)(n - 64)*64 + kh];
  }
  Bm[tid] = v;
}

// ---- gemm_mf v2: block-cooperative (VERIFIED R12) ----
__global__ __launch_bounds__(256) void gemm_mf(
    const float* __restrict__ A, int lda, int K,
    const bf16* __restrict__ Wf, bf16* __restrict__ outp, int M)
{
  const int l  = threadIdx.x & 63;
  const int w  = threadIdx.x >> 6;
  const int jl = l & 15, kg = l >> 4;
  const int row0 = blockIdx.x*64;
  __shared__ __align__(16) short As[64*104];    // 13,312 B

  const int K2 = K >> 1;
  const int tot = 64 * K2;
  for (int idx = threadIdx.x; idx < tot; idx += 256) {
    int r = idx / K2, c = idx - r*K2;
    int row = row0 + r;
    float2 a = (row < M) ? *(const float2*)(A + (size_t)row*lda + 2*c)
                         : make_float2(0.f, 0.f);
    *(unsigned*)(As + r*104 + 2*c) = bfpk(a.x, a.y);
  }
  __syncthreads();

  f32x4 acc[4][4];   // [mt][q], q owns n-tile 4q+w
#pragma unroll
  for (int mt = 0; mt < 4; ++mt)
#pragma unroll
    for (int q = 0; q < 4; ++q) acc[mt][q] = (f32x4){0.f,0.f,0.f,0.f};

  const short8v* Wl = (const short8v*)Wf + l;   // frag fi begins at Wl + fi*64
  const short* Ab = As + jl*104 + kg*8;
  const int NKS = K >> 5;          // 3 (K=96) or 2 (K=64)

  short8v cb[4];
#pragma unroll
  for (int q = 0; q < 4; ++q) cb[q] = Wl[(0*16 + 4*q + w)*64];
  for (int ks = 0; ks < NKS; ++ks) {
    short8v nb[4];
#pragma unroll
    for (int q = 0; q < 4; ++q) nb[q] = cb[q];
    if (ks + 1 < NKS) {
#pragma unroll
      for (int q = 0; q < 4; ++q) nb[q] = Wl[((ks+1)*16 + 4*q + w)*64];
    }
#pragma unroll
    for (int mt = 0; mt < 4; ++mt) {
      short8v a = *(const short8v*)(Ab + mt*16*104 + ks*32);
      acc[mt][0] = mfma16(a, cb[0], acc[mt][0]);
      acc[mt][1] = mfma16(a, cb[1], acc[mt][1]);
      acc[mt][2] = mfma16(a, cb[2], acc[mt][2]);
      acc[mt][3] = mfma16(a, cb[3], acc[mt][3]);
    }
#pragma unroll
    for (int q = 0; q < 4; ++q) cb[q] = nb[q];
  }

#pragma unroll
  for (int mt = 0; mt < 4; ++mt) {
#pragma unroll
    for (int r = 0; r < 4; ++r) {
      int row = row0 + mt*16 + kg*4 + r;
      if (row < M) {
        uint2 o;
        o.x = bfpk(acc[mt][0][r], acc[mt][1][r]);
        o.y = bfpk(acc[mt][2][r], acc[mt][3][r]);
        ((uint2*)outp)[(size_t)row*64 + (16*w + jl)] = o;
      }
    }
  }
}

// ---------------- CSR build (fused both phases, VERIFIED R14) ----------------
__global__ __launch_bounds__(256) void hist2(const int* __restrict__ dst1,
                                             const int* __restrict__ dst2,
                                             int* __restrict__ cntA, int C, int E){
  int e = blockIdx.x*256 + threadIdx.x;
  if (e >= E) return;
  atomicAdd(&cntA[dst1[e]], 1);                 // dst1 in [0,C)
  atomicAdd(&cntA[C + dst2[e] - V_NODES], 1);   // dst2 in [V,2V)
}
__global__ __launch_bounds__(256) void scanA(const int* __restrict__ cnt, int* __restrict__ part,
                                             int* __restrict__ bsum, int D){
  __shared__ int ts[256];
  int base = blockIdx.x*2048 + threadIdx.x*8;
  int v[8]; int s = 0;
#pragma unroll
  for (int i = 0; i < 8; ++i){ int idx = base+i; v[i] = (idx < D) ? cnt[idx] : 0; s += v[i]; }
  ts[threadIdx.x] = s; __syncthreads();
  for (int off = 1; off < 256; off <<= 1){
    int o = (threadIdx.x >= off) ? ts[threadIdx.x - off] : 0;
    __syncthreads();
    ts[threadIdx.x] += o;
    __syncthreads();
  }
  int run = ts[threadIdx.x] - s;
#pragma unroll
  for (int i = 0; i < 8; ++i){ int idx = base+i; if (idx < D) part[idx] = run; run += v[i]; }
  if (threadIdx.x == 255) bsum[blockIdx.x] = ts[255];
}
__global__ __launch_bounds__(256) void scanB(int* __restrict__ bsum, int nb){
  __shared__ int ts[256];
  int v = (threadIdx.x < nb) ? bsum[threadIdx.x] : 0;
  ts[threadIdx.x] = v; __syncthreads();
  for (int off = 1; off < 256; off <<= 1){
    int o = (threadIdx.x >= off) ? ts[threadIdx.x - off] : 0;
    __syncthreads();
    ts[threadIdx.x] += o;
    __syncthreads();
  }
  if (threadIdx.x < nb) bsum[threadIdx.x] = ts[threadIdx.x] - v;  // exclusive
}
__global__ __launch_bounds__(256) void scanC(const int* __restrict__ part, const int* __restrict__ bsum,
                                             int* __restrict__ rowptr, int* __restrict__ cursor,
                                             int D, int Eend){
  int idx = blockIdx.x*256 + threadIdx.x;
  if (idx < D){ int v = part[idx] + bsum[idx >> 11]; rowptr[idx] = v; cursor[idx] = v; }
  if (idx == 0) rowptr[D] = Eend;
}
__global__ __launch_bounds__(256) void scatter_k(const int* __restrict__ src, int soff,
                                                 const int* __restrict__ dst, int doff,
                                                 int* __restrict__ cursor, int* __restrict__ col,
                                                 int E, int pbase){
  int e = blockIdx.x*256 + threadIdx.x;
  if (e >= E) return;
  int p = atomicAdd(&cursor[dst[e]-doff], 1) - pbase;
  col[p] = src[e] - soff;
}

// ---- GATv2 aggregation (R17): 2 dsts per wave -> independent gather chains.
// Per-dst math/lane-map/epilogue verbatim R14 (verified); degree guards are
// wave-uniform (na/nb same across lanes) -> s_cbranch, no divergence.
__global__ __launch_bounds__(256) void gat_agg(
    const int* __restrict__ rowptr, const int* __restrict__ col,
    const bf16* __restrict__ xl, const bf16* __restrict__ xr,
    const float* __restrict__ att,
    bf16* __restrict__ agg, int D, int pbase)
{
  __shared__ short Tr4[4][256];
  int gw = (int)((blockIdx.x*256u + threadIdx.x) >> 6);
  int widA = 2*gw;
  if (widA >= D) return;
  const int widB = widA + 1;
  const bool hasB = (widB < D);
  const int l = threadIdx.x & 63;
  const int g = l >> 4, r = l & 15;
  short* Tw = Tr4[(threadIdx.x >> 6)];
  const float4 at = *(const float4*)(att + g*64 + 4*r);   // head g, dims 4r..4r+3

  uint2 urA = ((const uint2*)xr)[(size_t)widA*64 + l];
  uint2 urB = make_uint2(0u, 0u);
  if (hasB) urB = ((const uint2*)xr)[(size_t)widB*64 + l];
  const float xA0 = bflo(urA.x), xA1 = bfhi(urA.x), xA2 = bflo(urA.y), xA3 = bfhi(urA.y);
  const float xB0 = bflo(urB.x), xB1 = bfhi(urB.x), xB2 = bflo(urB.y), xB3 = bfhi(urB.y);

  const int pa0 = rowptr[widA] - pbase;
  const int pa1 = rowptr[widA+1] - pbase;      // == B's row start (widB = widA+1)
  const int pb1 = hasB ? (rowptr[widB+1] - pbase) : pa1;
  const int na = pa1 - pa0, nbd = pb1 - pa1;
  const int n = na > nbd ? na : nbd;

  float lsA=0.f, aA0=0.f, aA1=0.f, aA2=0.f, aA3=0.f;
  float lsB=0.f, aB0=0.f, aB1=0.f, aB2=0.f, aB3=0.f;
  for (int i = 0; i < n; ++i) {
    uint2 ua = make_uint2(0u,0u), ub = make_uint2(0u,0u);
    if (i < na)  ua = ((const uint2*)xl)[(size_t)col[pa0+i]*64 + l];
    if (i < nbd) ub = ((const uint2*)xl)[(size_t)col[pa1+i]*64 + l];
    if (i < na) {
      float x0 = bflo(ua.x), x1 = bfhi(ua.x), x2 = bflo(ua.y), x3 = bfhi(ua.y);
      float t0 = x0+xA0; t0 = fmaxf(t0, NEG*t0);
      float t1 = x1+xA1; t1 = fmaxf(t1, NEG*t1);
      float t2 = x2+xA2; t2 = fmaxf(t2, NEG*t2);
      float t3 = x3+xA3; t3 = fmaxf(t3, NEG*t3);
      float s = t0*at.x + t1*at.y + t2*at.z + t3*at.w;
      s += __shfl_xor(s, 8, 64);
      s += __shfl_xor(s, 4, 64);
      s += __shfl_xor(s, 2, 64);
      s += __shfl_xor(s, 1, 64);
      float pe = __expf(s);
      lsA += pe;
      aA0 += pe*x0; aA1 += pe*x1; aA2 += pe*x2; aA3 += pe*x3;
    }
    if (i < nbd) {
      float x0 = bflo(ub.x), x1 = bfhi(ub.x), x2 = bflo(ub.y), x3 = bfhi(ub.y);
      float t0 = x0+xB0; t0 = fmaxf(t0, NEG*t0);
      float t1 = x1+xB1; t1 = fmaxf(t1, NEG*t1);
      float t2 = x2+xB2; t2 = fmaxf(t2, NEG*t2);
      float t3 = x3+xB3; t3 = fmaxf(t3, NEG*t3);
      float s = t0*at.x + t1*at.y + t2*at.z + t3*at.w;
      s += __shfl_xor(s, 8, 64);
      s += __shfl_xor(s, 4, 64);
      s += __shfl_xor(s, 2, 64);
      s += __shfl_xor(s, 1, 64);
      float pe = __expf(s);
      lsB += pe;
      aB0 += pe*x0; aB1 += pe*x1; aB2 += pe*x2; aB3 += pe*x3;
    }
  }
  // epilogue A (verbatim R14 un-permute: col 64g+4r+s -> short idx 4*(4r+s)+g)
  {
    float inv = __builtin_amdgcn_rcpf(lsA + 1e-16f);
    Tw[16*r +  0 + g] = (short)f2bu(aA0*inv);
    Tw[16*r +  4 + g] = (short)f2bu(aA1*inv);
    Tw[16*r +  8 + g] = (short)f2bu(aA2*inv);
    Tw[16*r + 12 + g] = (short)f2bu(aA3*inv);
    asm volatile("" ::: "memory");
    ((uint2*)agg)[(size_t)widA*64 + l] = ((const uint2*)Tw)[l];
  }
  if (hasB) {
    asm volatile("" ::: "memory");   // order: A-read before B-write (in-order LDS per wave)
    float inv = __builtin_amdgcn_rcpf(lsB + 1e-16f);
    Tw[16*r +  0 + g] = (short)f2bu(aB0*inv);
    Tw[16*r +  4 + g] = (short)f2bu(aB1*inv);
    Tw[16*r +  8 + g] = (short)f2bu(aB2*inv);
    Tw[16*r + 12 + g] = (short)f2bu(aB3*inv);
    asm volatile("" ::: "memory");
    ((uint2*)agg)[(size_t)widB*64 + l] = ((const uint2*)Tw)[l];
  }
}

// ---- LN + GEMM + fused GRU gates (VERIFIED R11/R12 structure) ----
__global__ __launch_bounds__(256) void ln_gemm(
    const bf16* __restrict__ agg,      // [M][256] pos-layout bf16 (old layout)
    const float* __restrict__ gbias,
    const float* __restrict__ g, const float* __restrict__ b,
    const bf16* __restrict__ Wf,       // 160 frags x 512 bf16 (wprep_gf on Bm, K=320)
    const float* __restrict__ bih, const float* __restrict__ bhh,
    const float* __restrict__ x, int hrow0,
    float* __restrict__ out, int orow0, int M)
{
  __shared__ __align__(16) short At[64*328];   // 41,984 B block-shared
  const int l  = threadIdx.x & 63;
  const int w  = threadIdx.x >> 6;
  const int row0 = blockIdx.x*64;
  const int jl = l & 15, kg = l >> 4;

  // ---- LN phase: batch-load all 16 rows' operands, then compute ----
  float gb0 = gbias[l], gb1 = gbias[64+l], gb2 = gbias[128+l], gb3 = gbias[192+l];
  float gg0 = g[l],     gg1 = g[64+l],    gg2 = g[128+l],    gg3 = g[192+l];
  float bt0 = b[l],     bt1 = b[64+l],    bt2 = b[128+l],    bt3 = b[192+l];
  uint2 av[16]; float hp[16];
#pragma unroll
  for (int rr = 0; rr < 16; ++rr) {
    int row = row0 + w*16 + rr;
    av[rr] = make_uint2(0u, 0u);
    hp[rr] = 0.f;
    if (row < M) {
      av[rr] = ((const uint2*)agg)[(size_t)row*64 + l];
      hp[rr] = x[(size_t)(hrow0+row)*96 + 32 + l];
    }
  }
#pragma unroll
  for (int rr = 0; rr < 16; ++rr) {
    int rloc = w*16 + rr;
    float f0 = bflo(av[rr].x) + gb0, f1 = bfhi(av[rr].x) + gb1;
    float f2 = bflo(av[rr].y) + gb2, f3 = bfhi(av[rr].y) + gb3;
    float s = f0+f1+f2+f3, ss = f0*f0+f1*f1+f2*f2+f3*f3;
#pragma unroll
    for (int off = 32; off; off >>= 1){ s += __shfl_xor(s,off,64); ss += __shfl_xor(ss,off,64); }
    float mean = s * (1.f/256.f);
    float var  = ss * (1.f/256.f) - mean*mean;
    float rstd = rsqrtf(var + LN_EPS);
    short* Ar = At + rloc*328;
    Ar[l]       = (short)f2bu((f0-mean)*rstd*gg0 + bt0);   // u = l
    Ar[64 + l]  = (short)f2bu((f1-mean)*rstd*gg1 + bt1);   // u = 64+l
    Ar[128 + l] = (short)f2bu((f2-mean)*rstd*gg2 + bt2);   // u = 128+l
    Ar[192 + l] = (short)f2bu((f3-mean)*rstd*gg3 + bt3);   // u = 192+l
    Ar[256 + l] = (short)f2bu(hp[rr]);                      // h dim l
  }
  __syncthreads();

  // ---- GEMM: acc[mt][gate], gate 0=r(nt=w) 1=z(4+w) 2=inn(8+w) 3=hn(12+w) ----
  f32x4 acc[4][4];
#pragma unroll
  for (int mt = 0; mt < 4; ++mt)
#pragma unroll
    for (int q = 0; q < 4; ++q) acc[mt][q] = (f32x4){0.f,0.f,0.f,0.f};

  const short8v* Wl = (const short8v*)Wf + l;   // frag fi begins at Wl + fi*64
  const short* Ab = At + jl*328 + kg*8;

  short8v cb0 = Wl[(0*16 + w)*64];
  short8v cb1 = Wl[(0*16 + 4 + w)*64];
  short8v cb2 = Wl[(0*16 + 8 + w)*64];
#pragma unroll
  for (int ks = 0; ks < 10; ++ks) {
    short8v nb0 = cb0, nb1 = cb1, nb2 = cb2;
    if (ks < 9) {
      const int kn = ks + 1;
      nb0 = Wl[(kn*16 + w)*64];
      nb1 = Wl[(kn*16 + 4 + w)*64];
      nb2 = Wl[(kn*16 + ((kn < 8) ? 8 : 12) + w)*64];
    }
    const int gi = (ks < 8) ? 2 : 3;
#pragma unroll
    for (int mt = 0; mt < 4; ++mt) {
      short8v a = *(const short8v*)(Ab + mt*16*328 + ks*32);
      acc[mt][0]  = mfma16(a, cb0, acc[mt][0]);
      acc[mt][1]  = mfma16(a, cb1, acc[mt][1]);
      acc[mt][gi] = mfma16(a, cb2, acc[mt][gi]);
    }
    cb0 = nb0; cb1 = nb1; cb2 = nb2;
  }

  // ---- fused GRU epilogue (R10-verified mapping; batched h, fast gates) ----
  const int j = 16*w + jl;
  const float br = bih[j]      + bhh[j];
  const float bz = bih[64+j]   + bhh[64+j];
  const float bn = bih[128+j];
  const float bh = bhh[128+j];
  float hv[16];
#pragma unroll
  for (int mt = 0; mt < 4; ++mt)
#pragma unroll
    for (int r = 0; r < 4; ++r) {
      int row = row0 + mt*16 + kg*4 + r;
      hv[mt*4+r] = (row < M) ? x[(size_t)(hrow0+row)*96 + 32 + j] : 0.f;
    }
#pragma unroll
  for (int mt = 0; mt < 4; ++mt) {
#pragma unroll
    for (int r = 0; r < 4; ++r) {
      int row = row0 + mt*16 + kg*4 + r;
      if (row < M) {
        float rg = sigm_f(acc[mt][0][r] + br);
        float zg = sigm_f(acc[mt][1][r] + bz);
        float ng = tanh_f(acc[mt][2][r] + bn + rg*(acc[mt][3][r] + bh));
        out[(size_t)(orow0+row)*64 + j] = (1.f - zg)*ng + zg*hv[mt*4+r];
      }
    }
  }
}

__global__ void sentinel_kernel(float* out){ out[0] = 123456.0f; }

// ----------------------------------------------------------------------------
extern "C" void kernel_launch(void* const* d_in, const int* in_sizes, int n_in,
                              void* d_out, int out_size, void* d_ws, size_t ws_size,
                              hipStream_t stream)
{
  const float* x        = (const float*)d_in[0];
  const int*   ei       = (const int*)d_in[1];
  const float* v2c_Wl   = (const float*)d_in[3];
  const float* v2c_Wr   = (const float*)d_in[4];
  const float* v2c_att  = (const float*)d_in[5];
  const float* v2c_bias = (const float*)d_in[6];
  const float* c_ln_g   = (const float*)d_in[7];
  const float* c_ln_b   = (const float*)d_in[8];
  const float* c_Wih    = (const float*)d_in[9];
  const float* c_Whh    = (const float*)d_in[10];
  const float* c_bih    = (const float*)d_in[11];
  const float* c_bhh    = (const float*)d_in[12];
  const float* c2v_Wl   = (const float*)d_in[13];
  const float* c2v_Wr   = (const float*)d_in[14];
  const float* c2v_att  = (const float*)d_in[15];
  const float* c2v_bias = (const float*)d_in[16];
  const float* v_ln_g   = (const float*)d_in[17];
  const float* v_ln_b   = (const float*)d_in[18];
  const float* v_Wih    = (const float*)d_in[19];
  const float* v_Whh    = (const float*)d_in[20];
  const float* v_bih    = (const float*)d_in[21];
  const float* v_bhh    = (const float*)d_in[22];
  float* out = (float*)d_out;

  const int V = V_NODES;
  const int C = in_sizes[0] / 96 - V;
  const int E = in_sizes[1] / 4;
  const int* e0_1 = ei;                  // v2c src (offset V)
  const int* e1_1 = ei + (size_t)2*E;    // v2c dst (0-based clause)
  const int* e0_2 = ei + (size_t)E;      // c2v src (0-based clause idx)
  const int* e1_2 = ei + (size_t)3*E;    // c2v dst (offset V)

  // ---------------- workspace ----------------
  bf16* xl  = (bf16*)d_ws;                      // C*256
  bf16* xr  = xl + (size_t)C*256;               // C*256
  bf16* agg = xr + (size_t)C*256;               // C*256
  bf16* Wf2 = agg + (size_t)C*256;              // 81920 bf16 (GRU frag weights)
  float* Bm = (float*)(Wf2 + 81920);            // 81920 f32 (GRU B compose)
  bf16* Wgf = (bf16*)(Bm + 81920);              // 24576 bf16 (GAT frags, reused)
  int* cntA   = (int*)(Wgf + 24576);            // C+V (doubles as cursor)
  int* rowptr = cntA + C + V;                   // C+V+1
  int* part   = rowptr + C + V + 1;             // C+V
  int* bsum   = part + C + V;                   // 256
  int* col    = bsum + 256;                     // E
  size_t need = (size_t)C*256*2*3 + (size_t)81920*2 + (size_t)81920*4 +
                (size_t)24576*2 + ((size_t)3*(C+V) + 1 + 256 + (size_t)E) * 4;
  if (ws_size < need) {
    hipMemsetAsync(d_out, 0, (size_t)out_size*4, stream);
    sentinel_kernel<<<1,1,0,stream>>>(out);
    return;
  }

  const int EB = (E + 255)/256;
  const int DALL = C + V;

  // ================= fused CSR build (both phases) =================
  hipMemsetAsync(cntA, 0, (size_t)DALL*4, stream);
  hist2<<<EB, 256, 0, stream>>>(e1_1, e1_2, cntA, C, E);
  {
    int nb = (DALL + 2047)/2048;
    scanA<<<nb, 256, 0, stream>>>(cntA, part, bsum, DALL);
    scanB<<<1, 256, 0, stream>>>(bsum, nb);
    scanC<<<(DALL+255)/256, 256, 0, stream>>>(part, bsum, rowptr, cntA, DALL, 2*E);
  }

  // ================= phase 1: v2c -> clause GRU =================
  wprep_gp<<<96, 256, 0, stream>>>(v2c_Wl, Wgf, 96);
  gemm_mf<<<(V+63)/64, 256, 0, stream>>>(x, 96, 96, Wgf, xl, V);
  wprep_gp<<<96, 256, 0, stream>>>(v2c_Wr, Wgf, 96);
  gemm_mf<<<(C+63)/64, 256, 0, stream>>>(x + (size_t)V*96, 96, 96, Wgf, xr, C);
  scatter_k<<<EB, 256, 0, stream>>>(e0_1, V, e1_1, 0, cntA, col, E, 0);
  gat_agg<<<(C+7)/8, 256, 0, stream>>>(rowptr, col, xl, xr, v2c_att, agg, C, 0);
  wprep_bu<<<320, 256, 0, stream>>>(c_Wih, c_Whh, Bm);
  wprep_gf<<<320, 256, 0, stream>>>(Bm, Wf2, 320);
  ln_gemm<<<(C+63)/64, 256, 0, stream>>>(agg, v2c_bias, c_ln_g, c_ln_b, Wf2,
                                         c_bih, c_bhh, x, V, out, V, C);

  // ================= phase 2: c2v -> var GRU =================
  wprep_gp<<<64, 256, 0, stream>>>(c2v_Wl, Wgf, 64);
  gemm_mf<<<(C+63)/64, 256, 0, stream>>>(out + (size_t)V*64, 64, 64, Wgf, xl, C);
  wprep_gp<<<96, 256, 0, stream>>>(c2v_Wr, Wgf, 96);
  gemm_mf<<<(V+63)/64, 256, 0, stream>>>(x, 96, 96, Wgf, xr, V);
  scatter_k<<<EB, 256, 0, stream>>>(e0_2, 0, e1_2, V, cntA + C, col, E, E);
  gat_agg<<<(V+7)/8, 256, 0, stream>>>(rowptr + C, col, xl, xr, c2v_att, agg, V, E);
  wprep_bu<<<320, 256, 0, stream>>>(v_Wih, v_Whh, Bm);
  wprep_gf<<<320, 256, 0, stream>>>(Bm, Wf2, 320);
  ln_gemm<<<(V+63)/64, 256, 0, stream>>>(agg, c2v_bias, v_ln_g, v_ln_b, Wf2,
                                         v_bih, v_bhh, x, 0, out, 0, V);
}

// Round 18
// 1037.957 us; speedup vs baseline: 1.0460x; 1.0460x over previous
//
#include <hip/hip_runtime.h>
#include <hip/hip_bf16.h>
#include <cstdint>
#include <cstddef>

constexpr int V_NODES = 100000;
constexpr float NEG = 0.2f;
constexpr float LN_EPS = 1e-5f;
typedef __hip_bfloat16 bf16;

typedef __attribute__((ext_vector_type(8))) short short8v;
typedef __attribute__((ext_vector_type(4))) float f32x4;

__device__ inline float bflo(unsigned u){ return __uint_as_float(u << 16); }
__device__ inline float bfhi(unsigned u){ return __uint_as_float(u & 0xffff0000u); }
__device__ inline unsigned short f2bu(float x){ bf16 h = __float2bfloat16(x); return *reinterpret_cast<unsigned short*>(&h); }
__device__ inline unsigned bfpk(float x, float y){ return (unsigned)f2bu(x) | ((unsigned)f2bu(y) << 16); }

__device__ inline f32x4 mfma16(short8v a, short8v b, f32x4 c){
  return __builtin_amdgcn_mfma_f32_16x16x32_bf16(a, b, c, 0, 0, 0);
}

// fast gates: limit-correct at +/-inf (exp->inf => rcp->0)
__device__ inline float sigm_f(float v){ return __builtin_amdgcn_rcpf(1.f + __expf(-v)); }
__device__ inline float tanh_f(float t){ return 1.f - 2.f*__builtin_amdgcn_rcpf(__expf(2.f*t) + 1.f); }

// ---- weight prep for MFMA gemms: frag-major layout (VERIFIED R2) ----
__global__ __launch_bounds__(256) void wprep_gf(const float* __restrict__ W,
                                                bf16* __restrict__ Wf, int K){
  int tid = blockIdx.x*256 + threadIdx.x;   // over K*256
  if (tid >= K*256) return;
  int fi = tid >> 9, rem = tid & 511;
  int lane = rem >> 3, i = rem & 7;
  int ks = fi >> 4, nt = fi & 15;
  int n = nt*16 + (lane & 15);
  int k = ks*32 + ((lane >> 4) << 3) + i;
  Wf[tid] = __float2bfloat16(W[(size_t)k*256 + n]);
}

// ---- GAT weight prep with head-grouping permutation sigma (VERIFIED R7) ----
__global__ __launch_bounds__(256) void wprep_gp(const float* __restrict__ W,
                                                bf16* __restrict__ Wf, int K){
  int tid = blockIdx.x*256 + threadIdx.x;   // over K*256
  if (tid >= K*256) return;
  int fi = tid >> 9, rem = tid & 511;
  int lane = rem >> 3, i = rem & 7;
  int ks = fi >> 4, nt = fi & 15;
  int n = nt*16 + (lane & 15);
  int ns = (((n & 63) >> 4) << 6) + ((n & 15) << 2) + (n >> 6);   // sigma(n)
  int k = ks*32 + ((lane >> 4) << 3) + i;
  Wf[tid] = __float2bfloat16(W[(size_t)k*256 + ns]);
}

// ---- GRU B-matrix compose in PLAIN u-space (VERIFIED R4): Bm[320][256] f32 ----
__global__ __launch_bounds__(256) void wprep_bu(const float* __restrict__ Wih,
                                                const float* __restrict__ Whh,
                                                float* __restrict__ Bm){
  int tid = blockIdx.x*256 + threadIdx.x;   // over 320*256 = 81920
  if (tid >= 81920) return;
  int k = tid >> 8, n = tid & 255;
  float v = 0.f;
  if (k < 256) {
    if (n < 192) v = Wih[(size_t)n*256 + k];
  } else {
    int kh = k - 256;
    if (n < 128)       v = Whh[(size_t)n*64 + kh];
    else if (n >= 192) v = Whh[(size_t)(n - 64)*64 + kh];
  }
  Bm[tid] = v;
}

// ---- gemm_mf v2: block-cooperative (VERIFIED R12) ----
__global__ __launch_bounds__(256) void gemm_mf(
    const float* __restrict__ A, int lda, int K,
    const bf16* __restrict__ Wf, bf16* __restrict__ outp, int M)
{
  const int l  = threadIdx.x & 63;
  const int w  = threadIdx.x >> 6;
  const int jl = l & 15, kg = l >> 4;
  const int row0 = blockIdx.x*64;
  __shared__ __align__(16) short As[64*104];    // 13,312 B

  const int K2 = K >> 1;
  const int tot = 64 * K2;
  for (int idx = threadIdx.x; idx < tot; idx += 256) {
    int r = idx / K2, c = idx - r*K2;
    int row = row0 + r;
    float2 a = (row < M) ? *(const float2*)(A + (size_t)row*lda + 2*c)
                         : make_float2(0.f, 0.f);
    *(unsigned*)(As + r*104 + 2*c) = bfpk(a.x, a.y);
  }
  __syncthreads();

  f32x4 acc[4][4];   // [mt][q], q owns n-tile 4q+w
#pragma unroll
  for (int mt = 0; mt < 4; ++mt)
#pragma unroll
    for (int q = 0; q < 4; ++q) acc[mt][q] = (f32x4){0.f,0.f,0.f,0.f};

  const short8v* Wl = (const short8v*)Wf + l;   // frag fi begins at Wl + fi*64
  const short* Ab = As + jl*104 + kg*8;
  const int NKS = K >> 5;          // 3 (K=96) or 2 (K=64)

  short8v cb[4];
#pragma unroll
  for (int q = 0; q < 4; ++q) cb[q] = Wl[(0*16 + 4*q + w)*64];
  for (int ks = 0; ks < NKS; ++ks) {
    short8v nb[4];
#pragma unroll
    for (int q = 0; q < 4; ++q) nb[q] = cb[q];
    if (ks + 1 < NKS) {
#pragma unroll
      for (int q = 0; q < 4; ++q) nb[q] = Wl[((ks+1)*16 + 4*q + w)*64];
    }
#pragma unroll
    for (int mt = 0; mt < 4; ++mt) {
      short8v a = *(const short8v*)(Ab + mt*16*104 + ks*32);
      acc[mt][0] = mfma16(a, cb[0], acc[mt][0]);
      acc[mt][1] = mfma16(a, cb[1], acc[mt][1]);
      acc[mt][2] = mfma16(a, cb[2], acc[mt][2]);
      acc[mt][3] = mfma16(a, cb[3], acc[mt][3]);
    }
#pragma unroll
    for (int q = 0; q < 4; ++q) cb[q] = nb[q];
  }

#pragma unroll
  for (int mt = 0; mt < 4; ++mt) {
#pragma unroll
    for (int r = 0; r < 4; ++r) {
      int row = row0 + mt*16 + kg*4 + r;
      if (row < M) {
        uint2 o;
        o.x = bfpk(acc[mt][0][r], acc[mt][1][r]);
        o.y = bfpk(acc[mt][2][r], acc[mt][3][r]);
        ((uint2*)outp)[(size_t)row*64 + (16*w + jl)] = o;
      }
    }
  }
}

// ---------------- CSR build (fused both phases, VERIFIED R14) ----------------
__global__ __launch_bounds__(256) void hist2(const int* __restrict__ dst1,
                                             const int* __restrict__ dst2,
                                             int* __restrict__ cntA, int C, int E){
  int e = blockIdx.x*256 + threadIdx.x;
  if (e >= E) return;
  atomicAdd(&cntA[dst1[e]], 1);                 // dst1 in [0,C)
  atomicAdd(&cntA[C + dst2[e] - V_NODES], 1);   // dst2 in [V,2V)
}
__global__ __launch_bounds__(256) void scanA(const int* __restrict__ cnt, int* __restrict__ part,
                                             int* __restrict__ bsum, int D){
  __shared__ int ts[256];
  int base = blockIdx.x*2048 + threadIdx.x*8;
  int v[8]; int s = 0;
#pragma unroll
  for (int i = 0; i < 8; ++i){ int idx = base+i; v[i] = (idx < D) ? cnt[idx] : 0; s += v[i]; }
  ts[threadIdx.x] = s; __syncthreads();
  for (int off = 1; off < 256; off <<= 1){
    int o = (threadIdx.x >= off) ? ts[threadIdx.x - off] : 0;
    __syncthreads();
    ts[threadIdx.x] += o;
    __syncthreads();
  }
  int run = ts[threadIdx.x] - s;
#pragma unroll
  for (int i = 0; i < 8; ++i){ int idx = base+i; if (idx < D) part[idx] = run; run += v[i]; }
  if (threadIdx.x == 255) bsum[blockIdx.x] = ts[255];
}
__global__ __launch_bounds__(256) void scanB(int* __restrict__ bsum, int nb){
  __shared__ int ts[256];
  int v = (threadIdx.x < nb) ? bsum[threadIdx.x] : 0;
  ts[threadIdx.x] = v; __syncthreads();
  for (int off = 1; off < 256; off <<= 1){
    int o = (threadIdx.x >= off) ? ts[threadIdx.x - off] : 0;
    __syncthreads();
    ts[threadIdx.x] += o;
    __syncthreads();
  }
  if (threadIdx.x < nb) bsum[threadIdx.x] = ts[threadIdx.x] - v;  // exclusive
}
__global__ __launch_bounds__(256) void scanC(const int* __restrict__ part, const int* __restrict__ bsum,
                                             int* __restrict__ rowptr, int* __restrict__ cursor,
                                             int D, int Eend){
  int idx = blockIdx.x*256 + threadIdx.x;
  if (idx < D){ int v = part[idx] + bsum[idx >> 11]; rowptr[idx] = v; cursor[idx] = v; }
  if (idx == 0) rowptr[D] = Eend;
}
__global__ __launch_bounds__(256) void scatter_k(const int* __restrict__ src, int soff,
                                                 const int* __restrict__ dst, int doff,
                                                 int* __restrict__ cursor, int* __restrict__ col,
                                                 int E, int pbase){
  int e = blockIdx.x*256 + threadIdx.x;
  if (e >= E) return;
  int p = atomicAdd(&cursor[dst[e]-doff], 1) - pbase;
  col[p] = src[e] - soff;
}

// ---- GATv2 aggregation (VERIFIED R14: unroll-2, fmax-leaky, rcp, pbase) ----
__global__ __launch_bounds__(256) void gat_agg(
    const int* __restrict__ rowptr, const int* __restrict__ col,
    const bf16* __restrict__ xl, const bf16* __restrict__ xr,
    const float* __restrict__ att,
    bf16* __restrict__ agg, int D, int pbase)
{
  __shared__ short Tr4[4][256];
  int wid = (int)((blockIdx.x*256u + threadIdx.x) >> 6);
  if (wid >= D) return;
  const int l = threadIdx.x & 63;
  const int g = l >> 4, r = l & 15;
  short* Tw = Tr4[(threadIdx.x >> 6)];
  uint2 ur = ((const uint2*)xr)[(size_t)wid*64 + l];
  const float xr0 = bflo(ur.x), xr1 = bfhi(ur.x), xr2 = bflo(ur.y), xr3 = bfhi(ur.y);
  const float4 at = *(const float4*)(att + g*64 + 4*r);   // head g, dims 4r..4r+3
  float lsum = 0.f;
  float a0=0.f, a1=0.f, a2=0.f, a3=0.f;
  int p0 = rowptr[wid] - pbase, p1 = rowptr[wid+1] - pbase;
  int p = p0;
  for (; p + 1 < p1; p += 2){
    int ja = col[p], jb = col[p+1];
    uint2 ua = ((const uint2*)xl)[(size_t)ja*64 + l];
    uint2 ub = ((const uint2*)xl)[(size_t)jb*64 + l];
    float xa0 = bflo(ua.x), xa1 = bfhi(ua.x), xa2 = bflo(ua.y), xa3 = bfhi(ua.y);
    float xb0 = bflo(ub.x), xb1 = bfhi(ub.x), xb2 = bflo(ub.y), xb3 = bfhi(ub.y);
    float ta0=xa0+xr0, ta1=xa1+xr1, ta2=xa2+xr2, ta3=xa3+xr3;
    float tb0=xb0+xr0, tb1=xb1+xr1, tb2=xb2+xr2, tb3=xb3+xr3;
    ta0=fmaxf(ta0,NEG*ta0); ta1=fmaxf(ta1,NEG*ta1); ta2=fmaxf(ta2,NEG*ta2); ta3=fmaxf(ta3,NEG*ta3);
    tb0=fmaxf(tb0,NEG*tb0); tb1=fmaxf(tb1,NEG*tb1); tb2=fmaxf(tb2,NEG*tb2); tb3=fmaxf(tb3,NEG*tb3);
    float sa = ta0*at.x + ta1*at.y + ta2*at.z + ta3*at.w;
    float sb = tb0*at.x + tb1*at.y + tb2*at.z + tb3*at.w;
    sa += __shfl_xor(sa, 8, 64);  sb += __shfl_xor(sb, 8, 64);
    sa += __shfl_xor(sa, 4, 64);  sb += __shfl_xor(sb, 4, 64);
    sa += __shfl_xor(sa, 2, 64);  sb += __shfl_xor(sb, 2, 64);
    sa += __shfl_xor(sa, 1, 64);  sb += __shfl_xor(sb, 1, 64);
    float pea = __expf(sa), peb = __expf(sb);
    lsum += pea + peb;
    a0 += pea*xa0 + peb*xb0;
    a1 += pea*xa1 + peb*xb1;
    a2 += pea*xa2 + peb*xb2;
    a3 += pea*xa3 + peb*xb3;
  }
  if (p < p1){
    int j = col[p];
    uint2 uj = ((const uint2*)xl)[(size_t)j*64 + l];
    float x0 = bflo(uj.x), x1 = bfhi(uj.x), x2 = bflo(uj.y), x3 = bfhi(uj.y);
    float t0 = x0+xr0; t0 = fmaxf(t0, NEG*t0);
    float t1 = x1+xr1; t1 = fmaxf(t1, NEG*t1);
    float t2 = x2+xr2; t2 = fmaxf(t2, NEG*t2);
    float t3 = x3+xr3; t3 = fmaxf(t3, NEG*t3);
    float s = t0*at.x + t1*at.y + t2*at.z + t3*at.w;
    s += __shfl_xor(s, 8, 64);
    s += __shfl_xor(s, 4, 64);
    s += __shfl_xor(s, 2, 64);
    s += __shfl_xor(s, 1, 64);
    float pe = __expf(s);
    lsum += pe;
    a0 += pe*x0; a1 += pe*x1; a2 += pe*x2; a3 += pe*x3;
  }
  float inv = __builtin_amdgcn_rcpf(lsum + 1e-16f);
  // un-permute: value s (col 64g+4r+s) -> old-layout short idx 4*(4r+s) + g
  Tw[16*r +  0 + g] = (short)f2bu(a0*inv);
  Tw[16*r +  4 + g] = (short)f2bu(a1*inv);
  Tw[16*r +  8 + g] = (short)f2bu(a2*inv);
  Tw[16*r + 12 + g] = (short)f2bu(a3*inv);
  asm volatile("" ::: "memory");   // wave-private LDS write -> read fence
  ((uint2*)agg)[(size_t)wid*64 + l] = ((const uint2*)Tw)[l];
}

// ---- LN + GEMM + fused GRU gates (VERIFIED R11/R12 structure) ----
__global__ __launch_bounds__(256) void ln_gemm(
    const bf16* __restrict__ agg,      // [M][256] pos-layout bf16 (old layout)
    const float* __restrict__ gbias,
    const float* __restrict__ g, const float* __restrict__ b,
    const bf16* __restrict__ Wf,       // 160 frags x 512 bf16 (wprep_gf on Bm, K=320)
    const float* __restrict__ bih, const float* __restrict__ bhh,
    const float* __restrict__ x, int hrow0,
    float* __restrict__ out, int orow0, int M)
{
  __shared__ __align__(16) short At[64*328];   // 41,984 B block-shared
  const int l  = threadIdx.x & 63;
  const int w  = threadIdx.x >> 6;
  const int row0 = blockIdx.x*64;
  const int jl = l & 15, kg = l >> 4;

  // ---- LN phase: batch-load all 16 rows' operands, then compute ----
  float gb0 = gbias[l], gb1 = gbias[64+l], gb2 = gbias[128+l], gb3 = gbias[192+l];
  float gg0 = g[l],     gg1 = g[64+l],    gg2 = g[128+l],    gg3 = g[192+l];
  float bt0 = b[l],     bt1 = b[64+l],    bt2 = b[128+l],    bt3 = b[192+l];
  uint2 av[16]; float hp[16];
#pragma unroll
  for (int rr = 0; rr < 16; ++rr) {
    int row = row0 + w*16 + rr;
    av[rr] = make_uint2(0u, 0u);
    hp[rr] = 0.f;
    if (row < M) {
      av[rr] = ((const uint2*)agg)[(size_t)row*64 + l];
      hp[rr] = x[(size_t)(hrow0+row)*96 + 32 + l];
    }
  }
#pragma unroll
  for (int rr = 0; rr < 16; ++rr) {
    int rloc = w*16 + rr;
    float f0 = bflo(av[rr].x) + gb0, f1 = bfhi(av[rr].x) + gb1;
    float f2 = bflo(av[rr].y) + gb2, f3 = bfhi(av[rr].y) + gb3;
    float s = f0+f1+f2+f3, ss = f0*f0+f1*f1+f2*f2+f3*f3;
#pragma unroll
    for (int off = 32; off; off >>= 1){ s += __shfl_xor(s,off,64); ss += __shfl_xor(ss,off,64); }
    float mean = s * (1.f/256.f);
    float var  = ss * (1.f/256.f) - mean*mean;
    float rstd = rsqrtf(var + LN_EPS);
    short* Ar = At + rloc*328;
    Ar[l]       = (short)f2bu((f0-mean)*rstd*gg0 + bt0);   // u = l
    Ar[64 + l]  = (short)f2bu((f1-mean)*rstd*gg1 + bt1);   // u = 64+l
    Ar[128 + l] = (short)f2bu((f2-mean)*rstd*gg2 + bt2);   // u = 128+l
    Ar[192 + l] = (short)f2bu((f3-mean)*rstd*gg3 + bt3);   // u = 192+l
    Ar[256 + l] = (short)f2bu(hp[rr]);                      // h dim l
  }
  __syncthreads();

  // ---- GEMM: acc[mt][gate], gate 0=r(nt=w) 1=z(4+w) 2=inn(8+w) 3=hn(12+w) ----
  f32x4 acc[4][4];
#pragma unroll
  for (int mt = 0; mt < 4; ++mt)
#pragma unroll
    for (int q = 0; q < 4; ++q) acc[mt][q] = (f32x4){0.f,0.f,0.f,0.f};

  const short8v* Wl = (const short8v*)Wf + l;   // frag fi begins at Wl + fi*64
  const short* Ab = At + jl*328 + kg*8;

  short8v cb0 = Wl[(0*16 + w)*64];
  short8v cb1 = Wl[(0*16 + 4 + w)*64];
  short8v cb2 = Wl[(0*16 + 8 + w)*64];
#pragma unroll
  for (int ks = 0; ks < 10; ++ks) {
    short8v nb0 = cb0, nb1 = cb1, nb2 = cb2;
    if (ks < 9) {
      const int kn = ks + 1;
      nb0 = Wl[(kn*16 + w)*64];
      nb1 = Wl[(kn*16 + 4 + w)*64];
      nb2 = Wl[(kn*16 + ((kn < 8) ? 8 : 12) + w)*64];
    }
    const int gi = (ks < 8) ? 2 : 3;
#pragma unroll
    for (int mt = 0; mt < 4; ++mt) {
      short8v a = *(const short8v*)(Ab + mt*16*328 + ks*32);
      acc[mt][0]  = mfma16(a, cb0, acc[mt][0]);
      acc[mt][1]  = mfma16(a, cb1, acc[mt][1]);
      acc[mt][gi] = mfma16(a, cb2, acc[mt][gi]);
    }
    cb0 = nb0; cb1 = nb1; cb2 = nb2;
  }

  // ---- fused GRU epilogue (R10-verified mapping; batched h, fast gates) ----
  const int j = 16*w + jl;
  const float br = bih[j]      + bhh[j];
  const float bz = bih[64+j]   + bhh[64+j];
  const float bn = bih[128+j];
  const float bh = bhh[128+j];
  float hv[16];
#pragma unroll
  for (int mt = 0; mt < 4; ++mt)
#pragma unroll
    for (int r = 0; r < 4; ++r) {
      int row = row0 + mt*16 + kg*4 + r;
      hv[mt*4+r] = (row < M) ? x[(size_t)(hrow0+row)*96 + 32 + j] : 0.f;
    }
#pragma unroll
  for (int mt = 0; mt < 4; ++mt) {
#pragma unroll
    for (int r = 0; r < 4; ++r) {
      int row = row0 + mt*16 + kg*4 + r;
      if (row < M) {
        float rg = sigm_f(acc[mt][0][r] + br);
        float zg = sigm_f(acc[mt][1][r] + bz);
        float ng = tanh_f(acc[mt][2][r] + bn + rg*(acc[mt][3][r] + bh));
        out[(size_t)(orow0+row)*64 + j] = (1.f - zg)*ng + zg*hv[mt*4+r];
      }
    }
  }
}

__global__ void sentinel_kernel(float* out){ out[0] = 123456.0f; }

// ----------------------------------------------------------------------------
extern "C" void kernel_launch(void* const* d_in, const int* in_sizes, int n_in,
                              void* d_out, int out_size, void* d_ws, size_t ws_size,
                              hipStream_t stream)
{
  const float* x        = (const float*)d_in[0];
  const int*   ei       = (const int*)d_in[1];
  const float* v2c_Wl   = (const float*)d_in[3];
  const float* v2c_Wr   = (const float*)d_in[4];
  const float* v2c_att  = (const float*)d_in[5];
  const float* v2c_bias = (const float*)d_in[6];
  const float* c_ln_g   = (const float*)d_in[7];
  const float* c_ln_b   = (const float*)d_in[8];
  const float* c_Wih    = (const float*)d_in[9];
  const float* c_Whh    = (const float*)d_in[10];
  const float* c_bih    = (const float*)d_in[11];
  const float* c_bhh    = (const float*)d_in[12];
  const float* c2v_Wl   = (const float*)d_in[13];
  const float* c2v_Wr   = (const float*)d_in[14];
  const float* c2v_att  = (const float*)d_in[15];
  const float* c2v_bias = (const float*)d_in[16];
  const float* v_ln_g   = (const float*)d_in[17];
  const float* v_ln_b   = (const float*)d_in[18];
  const float* v_Wih    = (const float*)d_in[19];
  const float* v_Whh    = (const float*)d_in[20];
  const float* v_bih    = (const float*)d_in[21];
  const float* v_bhh    = (const float*)d_in[22];
  float* out = (float*)d_out;

  const int V = V_NODES;
  const int C = in_sizes[0] / 96 - V;
  const int E = in_sizes[1] / 4;
  const int* e0_1 = ei;                  // v2c src (offset V)
  const int* e1_1 = ei + (size_t)2*E;    // v2c dst (0-based clause)
  const int* e0_2 = ei + (size_t)E;      // c2v src (0-based clause idx)
  const int* e1_2 = ei + (size_t)3*E;    // c2v dst (offset V)

  // ---------------- workspace ----------------
  bf16* xl  = (bf16*)d_ws;                      // C*256
  bf16* xr  = xl + (size_t)C*256;               // C*256
  bf16* agg = xr + (size_t)C*256;               // C*256
  bf16* Wf2 = agg + (size_t)C*256;              // 81920 bf16 (GRU frag weights)
  float* Bm = (float*)(Wf2 + 81920);            // 81920 f32 (GRU B compose)
  bf16* Wgf = (bf16*)(Bm + 81920);              // 24576 bf16 (GAT frags, reused)
  int* cntA   = (int*)(Wgf + 24576);            // C+V (doubles as cursor)
  int* rowptr = cntA + C + V;                   // C+V+1
  int* part   = rowptr + C + V + 1;             // C+V
  int* bsum   = part + C + V;                   // 256
  int* col    = bsum + 256;                     // E
  size_t need = (size_t)C*256*2*3 + (size_t)81920*2 + (size_t)81920*4 +
                (size_t)24576*2 + ((size_t)3*(C+V) + 1 + 256 + (size_t)E) * 4;
  if (ws_size < need) {
    hipMemsetAsync(d_out, 0, (size_t)out_size*4, stream);
    sentinel_kernel<<<1,1,0,stream>>>(out);
    return;
  }

  const int EB = (E + 255)/256;
  const int DALL = C + V;

  // ================= fused CSR build (both phases) =================
  hipMemsetAsync(cntA, 0, (size_t)DALL*4, stream);
  hist2<<<EB, 256, 0, stream>>>(e1_1, e1_2, cntA, C, E);
  {
    int nb = (DALL + 2047)/2048;
    scanA<<<nb, 256, 0, stream>>>(cntA, part, bsum, DALL);
    scanB<<<1, 256, 0, stream>>>(bsum, nb);
    scanC<<<(DALL+255)/256, 256, 0, stream>>>(part, bsum, rowptr, cntA, DALL, 2*E);
  }

  // ================= phase 1: v2c -> clause GRU =================
  wprep_gp<<<96, 256, 0, stream>>>(v2c_Wl, Wgf, 96);
  gemm_mf<<<(V+63)/64, 256, 0, stream>>>(x, 96, 96, Wgf, xl, V);
  wprep_gp<<<96, 256, 0, stream>>>(v2c_Wr, Wgf, 96);
  gemm_mf<<<(C+63)/64, 256, 0, stream>>>(x + (size_t)V*96, 96, 96, Wgf, xr, C);
  scatter_k<<<EB, 256, 0, stream>>>(e0_1, V, e1_1, 0, cntA, col, E, 0);
  gat_agg<<<(C+3)/4, 256, 0, stream>>>(rowptr, col, xl, xr, v2c_att, agg, C, 0);
  wprep_bu<<<320, 256, 0, stream>>>(c_Wih, c_Whh, Bm);
  wprep_gf<<<320, 256, 0, stream>>>(Bm, Wf2, 320);
  ln_gemm<<<(C+63)/64, 256, 0, stream>>>(agg, v2c_bias, c_ln_g, c_ln_b, Wf2,
                                         c_bih, c_bhh, x, V, out, V, C);

  // ================= phase 2: c2v -> var GRU =================
  wprep_gp<<<64, 256, 0, stream>>>(c2v_Wl, Wgf, 64);
  gemm_mf<<<(C+63)/64, 256, 0, stream>>>(out + (size_t)V*64, 64, 64, Wgf, xl, C);
  wprep_gp<<<96, 256, 0, stream>>>(c2v_Wr, Wgf, 96);
  gemm_mf<<<(V+63)/64, 256, 0, stream>>>(x, 96, 96, Wgf, xr, V);
  scatter_k<<<EB, 256, 0, stream>>>(e0_2, 0, e1_2, V, cntA + C, col, E, E);
  gat_agg<<<(V+3)/4, 256, 0, stream>>>(rowptr + C, col, xl, xr, c2v_att, agg, V, E);
  wprep_bu<<<320, 256, 0, stream>>>(v_Wih, v_Whh, Bm);
  wprep_gf<<<320, 256, 0, stream>>>(Bm, Wf2, 320);
  ln_gemm<<<(V+63)/64, 256, 0, stream>>>(agg, c2v_bias, v_ln_g, v_ln_b, Wf2,
                                         v_bih, v_bhh, x, 0, out, 0, V);
}